// Round 6
// baseline (533.707 us; speedup 1.0000x reference)
//
#include <hip/hip_runtime.h>
#include <cstdint>
#include <math.h>

typedef unsigned short u16;
typedef __attribute__((ext_vector_type(8))) short bf16x8;  // 8 bf16 (4 VGPRs)
typedef __attribute__((ext_vector_type(4))) float f32x4;   // MFMA acc

#define DEVI __device__ __forceinline__

DEVI u16 f2bf(float f) {
  union { float f; uint32_t u; } v; v.f = f;
  return (u16)((v.u + 0x7FFFu + ((v.u >> 16) & 1u)) >> 16);  // RNE
}
DEVI float bf2f(u16 h) {
  union { uint32_t u; float f; } v; v.u = ((uint32_t)h) << 16;
  return v.f;
}

// async global->LDS, 16B per lane. LDS dst = wave-uniform base + lane*16.
DEVI void gload16(const void* g, void* l) {
  __builtin_amdgcn_global_load_lds(
      (const __attribute__((address_space(1))) void*)g,
      (__attribute__((address_space(3))) void*)l, 16, 0, 0);
}

// tanh-form GELU: u*(1 - 1/(1+e^{2*0.79788456*(u+0.044715u^3)}))
DEVI float gelu_fast(float u) {
  float u2 = u * u;
  float t = __builtin_fmaf(0.044715f * u2, u, u);
  float e = __expf(1.5957691216057308f * t);
  float r = __builtin_amdgcn_rcpf(1.0f + e);
  return u - u * r;
}

// ---------------------------------------------------------------------------
// fp32 W[K][N] -> bf16 Wt[N][K] transpose-convert, one 64x64 tile via LDS
// ---------------------------------------------------------------------------
DEVI void tcvt_body(const float* __restrict__ W, u16* __restrict__ Wt,
                    int Kd, int N, int n0, int k0, float* t) {
  const int r = threadIdx.x >> 4, c4 = (threadIdx.x & 15) * 4;
#pragma unroll
  for (int p = 0; p < 4; ++p) {
    int row = p * 16 + r;
    float4 f = *(const float4*)(W + (size_t)(k0 + row) * N + n0 + c4);
    *(float4*)&t[row * 68 + c4] = f;
  }
  __syncthreads();
#pragma unroll
  for (int p = 0; p < 4; ++p) {
    int n = p * 16 + r;
    float v0 = t[(c4 + 0) * 68 + n];
    float v1 = t[(c4 + 1) * 68 + n];
    float v2 = t[(c4 + 2) * 68 + n];
    float v3 = t[(c4 + 3) * 68 + n];
    uint32_t lo = (uint32_t)f2bf(v0) | ((uint32_t)f2bf(v1) << 16);
    uint32_t hi = (uint32_t)f2bf(v2) | ((uint32_t)f2bf(v3) << 16);
    *(uint2*)(Wt + (size_t)(n0 + n) * Kd + k0 + c4) = make_uint2(lo, hi);
  }
}

// ---------------------------------------------------------------------------
// Fused prep: all weight transpose-converts + x convert + bias concat.
// grid.x = 7180: [0,1024) Wq/Wk/Wv/Wo; [1024,2048) W1; [2048,3072) W2;
// [3072,7168) x cvt; [7168,7180) bias concat.
// ---------------------------------------------------------------------------
__global__ __launch_bounds__(256)
void prep_kernel(const float* __restrict__ Wq, const float* __restrict__ Wk,
                 const float* __restrict__ Wv, const float* __restrict__ Wo,
                 const float* __restrict__ W1, const float* __restrict__ W2,
                 const float* __restrict__ x, const float* __restrict__ bq,
                 const float* __restrict__ bk, const float* __restrict__ bv,
                 u16* __restrict__ WqkvT, u16* __restrict__ WoT,
                 u16* __restrict__ W1T, u16* __restrict__ W2T,
                 u16* __restrict__ xb, float* __restrict__ bqkv)
{
  __shared__ float t[64 * 68];
  const int b = blockIdx.x;
  if (b < 1024) {
    int wsel = b >> 8, tt = b & 255;
    const float* W = (wsel == 0) ? Wq : (wsel == 1) ? Wk : (wsel == 2) ? Wv : Wo;
    u16* dst = (wsel == 3) ? WoT : WqkvT + (size_t)wsel * 1024 * 1024;
    tcvt_body(W, dst, 1024, 1024, (tt & 15) * 64, (tt >> 4) * 64, t);
  } else if (b < 2048) {
    int tt = b - 1024;
    tcvt_body(W1, W1T, 1024, 4096, (tt & 63) * 64, (tt >> 6) * 64, t);
  } else if (b < 3072) {
    int tt = b - 2048;
    tcvt_body(W2, W2T, 4096, 1024, (tt & 15) * 64, (tt >> 4) * 64, t);
  } else if (b < 7168) {
    int i = ((b - 3072) * 256 + threadIdx.x) * 4;
    float4 f = *(const float4*)(x + i);
    uint32_t lo = (uint32_t)f2bf(f.x) | ((uint32_t)f2bf(f.y) << 16);
    uint32_t hi = (uint32_t)f2bf(f.z) | ((uint32_t)f2bf(f.w) << 16);
    *(uint2*)(xb + i) = make_uint2(lo, hi);
  } else {
    int i = (b - 7168) * 256 + threadIdx.x;  // 0..3071
    const float* s = (i < 1024) ? bq : ((i < 2048) ? bk : bv);
    bqkv[i] = s[i & 1023];
  }
}

// ---------------------------------------------------------------------------
// GEMM: 128x128 tile, BK=64 (two stride-32 half-buffers), 256 thr (4 waves).
// Default: MFMA with SWAPPED operands -> acc[i][j] = D[n][m], lane holds 4
// consecutive n for fixed m -> packed epilogue stores along n.
//   m_global = m0 + wm + i*16 + (lane&15);  n_global = n0 + wn + j*16 + rq + r
// V-blocks (MODE 0, n0>=2048) use UNSWAPPED order -> D[m][n], lane holds 4
// consecutive m for fixed n -> packed Vt[d][m] stores along m.
// MODE 0: fused QKV — n0<2048 -> QKb[m][n] bf16+bias; n0>=2048 -> Vt[n-2048][m].
// MODE 1: bf16 out + bias + fast GELU.
// MODE 2: split-K gridDim.z=2; z0 -> bf16+bias to C0; z1 -> bf16 raw to C1.
// L2 supertile swizzle: GROUP=8 m-tiles per band.
// ---------------------------------------------------------------------------
template<int MODE>
__global__ __launch_bounds__(256, 4)
void gemm_kernel(const u16* __restrict__ A, const u16* __restrict__ Bt,
                 const float* __restrict__ bias, void* __restrict__ C0,
                 void* __restrict__ C1, int N, int Kfull, int Kpart)
{
  __shared__ u16 As0[128 * 32], As1[128 * 32];
  __shared__ u16 Bs0[128 * 32], Bs1[128 * 32];
  const int tid = threadIdx.x;
  // supertile swizzle (8 m-tiles per band)
  const int nbx = gridDim.x, nby = gridDim.y;
  int lin = blockIdx.y * nbx + blockIdx.x;
  int band = lin / (8 * nbx);
  int rem = lin - band * (8 * nbx);
  int gsz = min(nby - band * 8, 8);
  const int m0 = (band * 8 + rem % gsz) * 128;
  const int n0 = (rem / gsz) * 128;
  const int kbase = (MODE == 2) ? (int)blockIdx.z * Kpart : 0;
  const int w = tid >> 6, lane = tid & 63;
  const int wm = (w >> 1) * 64, wn = (w & 1) * 64;
  const int mr = lane & 15, ko = (lane >> 4) * 8;
  const int rq = (lane >> 4) * 4;
  const int w32 = w * 32;
  const bool vblk = (MODE == 0) && (n0 >= 2048);

  f32x4 acc[4][4];
#pragma unroll
  for (int i = 0; i < 4; ++i)
#pragma unroll
    for (int j = 0; j < 4; ++j) {
      f32x4 z = {0.f, 0.f, 0.f, 0.f};
      acc[i][j] = z;
    }

  // staging: per gload16, 64 lanes cover 16 rows x 32 k (u16)
  const int lr = lane >> 2, lk = (lane & 3) * 8;
  const u16* aG = A  + (size_t)(m0 + w32 + lr) * Kfull + kbase + lk;
  const u16* bG = Bt + (size_t)(n0 + w32 + lr) * Kfull + kbase + lk;
  u16* aD00 = &As0[(w32 +  0) * 32];
  u16* aD01 = &As0[(w32 + 16) * 32];
  u16* aD10 = &As1[(w32 +  0) * 32];
  u16* aD11 = &As1[(w32 + 16) * 32];
  u16* bD00 = &Bs0[(w32 +  0) * 32];
  u16* bD01 = &Bs0[(w32 + 16) * 32];
  u16* bD10 = &Bs1[(w32 +  0) * 32];
  u16* bD11 = &Bs1[(w32 + 16) * 32];
  const size_t row16 = (size_t)16 * Kfull;

  for (int k0 = 0; k0 < Kpart; k0 += 64) {
    gload16(aG + k0,              aD00);
    gload16(aG + row16 + k0,      aD01);
    gload16(aG + k0 + 32,         aD10);
    gload16(aG + row16 + k0 + 32, aD11);
    gload16(bG + k0,              bD00);
    gload16(bG + row16 + k0,      bD01);
    gload16(bG + k0 + 32,         bD10);
    gload16(bG + row16 + k0 + 32, bD11);
    __syncthreads();
#pragma unroll
    for (int s = 0; s < 2; ++s) {
      const u16* Ap = s ? As1 : As0;
      const u16* Bp = s ? Bs1 : Bs0;
      bf16x8 af[4], bf[4];
#pragma unroll
      for (int i = 0; i < 4; ++i)
        af[i] = *(const bf16x8*)&Ap[(wm + i * 16 + mr) * 32 + ko];
#pragma unroll
      for (int j = 0; j < 4; ++j)
        bf[j] = *(const bf16x8*)&Bp[(wn + j * 16 + mr) * 32 + ko];
      if (!vblk) {
#pragma unroll
        for (int i = 0; i < 4; ++i)
#pragma unroll
          for (int j = 0; j < 4; ++j)
            acc[i][j] = __builtin_amdgcn_mfma_f32_16x16x32_bf16(bf[j], af[i], acc[i][j], 0, 0, 0);
      } else {
#pragma unroll
        for (int i = 0; i < 4; ++i)
#pragma unroll
          for (int j = 0; j < 4; ++j)
            acc[i][j] = __builtin_amdgcn_mfma_f32_16x16x32_bf16(af[i], bf[j], acc[i][j], 0, 0, 0);
      }
    }
    __syncthreads();
  }

  if (MODE == 0) {
    if (!vblk) {      // Q,K -> QKb [4096][2048], packed along n
#pragma unroll
      for (int i = 0; i < 4; ++i) {
        size_t mrow = (size_t)(m0 + wm + i * 16 + mr) * 2048;
#pragma unroll
        for (int j = 0; j < 4; ++j) {
          int nb = n0 + wn + j * 16 + rq;
          float4 b4 = *(const float4*)&bias[nb];
          uint32_t lo = (uint32_t)f2bf(acc[i][j][0] + b4.x) |
                        ((uint32_t)f2bf(acc[i][j][1] + b4.y) << 16);
          uint32_t hi = (uint32_t)f2bf(acc[i][j][2] + b4.z) |
                        ((uint32_t)f2bf(acc[i][j][3] + b4.w) << 16);
          *(uint2*)((u16*)C0 + mrow + nb) = make_uint2(lo, hi);
        }
      }
    } else {          // V -> Vt [1024][4096], D[m][n]: packed along m
#pragma unroll
      for (int i = 0; i < 4; ++i) {
        int mg = m0 + wm + i * 16 + rq;   // 4 consecutive m
#pragma unroll
        for (int j = 0; j < 4; ++j) {
          int ng = n0 + wn + j * 16 + mr; // one n per lane
          float bv = bias[ng];
          int d = ng - 2048;
          uint32_t lo = (uint32_t)f2bf(acc[i][j][0] + bv) |
                        ((uint32_t)f2bf(acc[i][j][1] + bv) << 16);
          uint32_t hi = (uint32_t)f2bf(acc[i][j][2] + bv) |
                        ((uint32_t)f2bf(acc[i][j][3] + bv) << 16);
          *(uint2*)((u16*)C1 + (size_t)d * 4096 + mg) = make_uint2(lo, hi);
        }
      }
    }
  } else {
    const bool part1 = (MODE == 2) && (blockIdx.z == 1);
#pragma unroll
    for (int i = 0; i < 4; ++i) {
      size_t mrow = (size_t)(m0 + wm + i * 16 + mr) * N;
#pragma unroll
      for (int j = 0; j < 4; ++j) {
        int nb = n0 + wn + j * 16 + rq;
        float v0 = acc[i][j][0], v1 = acc[i][j][1];
        float v2 = acc[i][j][2], v3 = acc[i][j][3];
        if (!part1) {
          float4 b4 = *(const float4*)&bias[nb];
          v0 += b4.x; v1 += b4.y; v2 += b4.z; v3 += b4.w;
        }
        if (MODE == 1) {
          v0 = gelu_fast(v0); v1 = gelu_fast(v1);
          v2 = gelu_fast(v2); v3 = gelu_fast(v3);
        }
        uint32_t lo = (uint32_t)f2bf(v0) | ((uint32_t)f2bf(v1) << 16);
        uint32_t hi = (uint32_t)f2bf(v2) | ((uint32_t)f2bf(v3) << 16);
        u16* dst = part1 ? (u16*)C1 : (u16*)C0;
        *(uint2*)(dst + mrow + nb) = make_uint2(lo, hi);
      }
    }
  }
}

// ---------------------------------------------------------------------------
// Banded MFMA flash attention, simplified softmax. QK^T swapped -> S[t][q]:
// lane owns ONE q -> packed b64 P-writes, scalar l. PV swapped -> O[d][q].
// ---------------------------------------------------------------------------
__global__ __launch_bounds__(256)
void attn_kernel(const u16* __restrict__ QKb, const u16* __restrict__ Vt,
                 u16* __restrict__ ctx)
{
  const int KS = 2048, HD = 1024;
  __shared__ u16 Qs[64 * 80];
  __shared__ u16 Ks[64 * 80];
  __shared__ u16 Vts[64 * 72];   // [d][t]
  __shared__ u16 Ps[64 * 72];    // [q][t]

  const int qt = blockIdx.x, hh = blockIdx.y, bb = blockIdx.z;
  const int s0 = qt * 64;
  const int tid = threadIdx.x, w = tid >> 6, lane = tid & 63;
  const int mr = lane & 15, ko = (lane >> 4) * 8, rq = (lane >> 4) * 4;
  const int sr = tid >> 3, sc = (tid & 7) * 8;
  const int vrow = tid >> 2, vtc = (tid & 3) * 16;
  const float qsc = 0.022097086912079608f;  // 1/sqrt(2048)
  const int qg = s0 + w * 16 + mr;          // this lane's query row

#pragma unroll
  for (int p = 0; p < 2; ++p) {
    int row = p * 32 + sr;
    uint4 u = *(const uint4*)(QKb + (size_t)(bb * KS + s0 + row) * 2048 + hh * 64 + sc);
    *(uint4*)&Qs[row * 80 + sc] = u;
  }

  f32x4 accO[4];
#pragma unroll
  for (int j = 0; j < 4; ++j) { f32x4 z = {0.f,0.f,0.f,0.f}; accO[j] = z; }
  float lsum = 0.f;

  for (int c = 0; c < 9; ++c) {
    int tb = s0 - 256 + c * 64;
    if (tb < 0 || tb >= KS) continue;
    __syncthreads();
#pragma unroll
    for (int p = 0; p < 2; ++p) {
      int row = p * 32 + sr;
      uint4 uk = *(const uint4*)(QKb + (size_t)(bb * KS + tb + row) * 2048 + 1024 + hh * 64 + sc);
      *(uint4*)&Ks[row * 80 + sc] = uk;
    }
    {
      const u16* vsrc = Vt + (size_t)(hh * 64 + vrow) * 4096 + bb * KS + tb + vtc;
      *(uint4*)&Vts[vrow * 72 + vtc]     = *(const uint4*)vsrc;
      *(uint4*)&Vts[vrow * 72 + vtc + 8] = *(const uint4*)(vsrc + 8);
    }
    __syncthreads();

    // S = K Q^T (swapped): sacc[j] holds S[t= tb+j*16+rq+r][q= qg]
    f32x4 sacc[4];
#pragma unroll
    for (int j = 0; j < 4; ++j) { f32x4 z = {0.f,0.f,0.f,0.f}; sacc[j] = z; }
#pragma unroll
    for (int s = 0; s < 2; ++s) {
      bf16x8 aq = *(const bf16x8*)&Qs[(w * 16 + mr) * 80 + s * 32 + ko];
#pragma unroll
      for (int j = 0; j < 4; ++j) {
        bf16x8 bk = *(const bf16x8*)&Ks[(j * 16 + mr) * 80 + s * 32 + ko];
        sacc[j] = __builtin_amdgcn_mfma_f32_16x16x32_bf16(bk, aq, sacc[j], 0, 0, 0);
      }
    }

    // p = expf(s) (bounded scores); packed b64 P-writes; scalar l per lane
#pragma unroll
    for (int j = 0; j < 4; ++j) {
      int tgb = tb + j * 16 + rq;
      float p0, p1, p2, p3;
      {
        int d0 = qg - tgb;
        float s_ = sacc[j][0] * qsc;
        p0 = (d0 > 256 || d0 < -256) ? 0.f : __expf(s_);
        int d1 = d0 - 1; s_ = sacc[j][1] * qsc;
        p1 = (d1 > 256 || d1 < -256) ? 0.f : __expf(s_);
        int d2 = d0 - 2; s_ = sacc[j][2] * qsc;
        p2 = (d2 > 256 || d2 < -256) ? 0.f : __expf(s_);
        int d3 = d0 - 3; s_ = sacc[j][3] * qsc;
        p3 = (d3 > 256 || d3 < -256) ? 0.f : __expf(s_);
      }
      lsum += p0 + p1 + p2 + p3;
      uint32_t lo = (uint32_t)f2bf(p0) | ((uint32_t)f2bf(p1) << 16);
      uint32_t hi = (uint32_t)f2bf(p2) | ((uint32_t)f2bf(p3) << 16);
      *(uint2*)&Ps[(w * 16 + mr) * 72 + j * 16 + rq] = make_uint2(lo, hi);
    }
    // O += V^T P^T (swapped): accO[j] = O[d= j*16+rq+r][q= qg]
#pragma unroll
    for (int s = 0; s < 2; ++s) {
      bf16x8 ap = *(const bf16x8*)&Ps[(w * 16 + mr) * 72 + s * 32 + ko];
#pragma unroll
      for (int j = 0; j < 4; ++j) {
        bf16x8 bv = *(const bf16x8*)&Vts[(j * 16 + mr) * 72 + s * 32 + ko];
        accO[j] = __builtin_amdgcn_mfma_f32_16x16x32_bf16(bv, ap, accO[j], 0, 0, 0);
      }
    }
  }

  float l = lsum;
  l += __shfl_xor(l, 16, 64);
  l += __shfl_xor(l, 32, 64);
  float inv = 1.f / l;
  size_t base = (size_t)(bb * KS + qg) * HD + hh * 64;
#pragma unroll
  for (int j = 0; j < 4; ++j) {
    uint32_t lo = (uint32_t)f2bf(accO[j][0] * inv) | ((uint32_t)f2bf(accO[j][1] * inv) << 16);
    uint32_t hi = (uint32_t)f2bf(accO[j][2] * inv) | ((uint32_t)f2bf(accO[j][3] * inv) << 16);
    *(uint2*)(ctx + base + j * 16 + rq) = make_uint2(lo, hi);
  }
}

// ---------------------------------------------------------------------------
// LayerNorm(p0 + p1 + res) over D=1024; all inputs bf16.
// OUT32=0 -> bf16 out; OUT32=1 -> fp32 out.
// ---------------------------------------------------------------------------
DEVI void bfadd4(const u16* p, size_t base, float& v0, float& v1, float& v2, float& v3) {
  uint2 u = *(const uint2*)(p + base);
  v0 += bf2f((u16)(u.x & 0xFFFFu));
  v1 += bf2f((u16)(u.x >> 16));
  v2 += bf2f((u16)(u.y & 0xFFFFu));
  v3 += bf2f((u16)(u.y >> 16));
}

template<int OUT32>
__global__ __launch_bounds__(256)
void ln_kernel(const u16* __restrict__ p0, const u16* __restrict__ p1,
               const u16* __restrict__ res, const float* __restrict__ g,
               const float* __restrict__ be, void* __restrict__ out)
{
  __shared__ float red[8];
  const int row = blockIdx.x, tid = threadIdx.x;
  const int w = tid >> 6, lane = tid & 63;
  size_t base = (size_t)row * 1024 + tid * 4;
  float v0 = 0.f, v1 = 0.f, v2 = 0.f, v3 = 0.f;
  bfadd4(p0, base, v0, v1, v2, v3);
  bfadd4(p1, base, v0, v1, v2, v3);
  bfadd4(res, base, v0, v1, v2, v3);
  float s1 = v0 + v1 + v2 + v3;
  float s2 = v0 * v0 + v1 * v1 + v2 * v2 + v3 * v3;
#pragma unroll
  for (int o = 32; o > 0; o >>= 1) {
    s1 += __shfl_xor(s1, o, 64);
    s2 += __shfl_xor(s2, o, 64);
  }
  if (lane == 0) { red[w] = s1; red[4 + w] = s2; }
  __syncthreads();
  s1 = red[0] + red[1] + red[2] + red[3];
  s2 = red[4] + red[5] + red[6] + red[7];
  float mu = s1 * (1.f / 1024.f);
  float var = s2 * (1.f / 1024.f) - mu * mu;
  float rs = rsqrtf(var + 1e-5f);
  float4 gv = *(const float4*)(g + tid * 4);
  float4 bv = *(const float4*)(be + tid * 4);
  float o0 = (v0 - mu) * rs * gv.x + bv.x;
  float o1 = (v1 - mu) * rs * gv.y + bv.y;
  float o2 = (v2 - mu) * rs * gv.z + bv.z;
  float o3 = (v3 - mu) * rs * gv.w + bv.w;
  if (OUT32) {
    float4 ov; ov.x = o0; ov.y = o1; ov.z = o2; ov.w = o3;
    *(float4*)((float*)out + base) = ov;
  } else {
    uint32_t lo = (uint32_t)f2bf(o0) | ((uint32_t)f2bf(o1) << 16);
    uint32_t hi = (uint32_t)f2bf(o2) | ((uint32_t)f2bf(o3) << 16);
    *(uint2*)((u16*)out + base) = make_uint2(lo, hi);
  }
}

// ---------------------------------------------------------------------------
// ws layout (64 MiB), MiB offsets, lifetime-verified:
//  [0,8)   W1T (prep->G3)        -> Y0b bf16 (G4->LN2)
//  [8,16)  xb (prep->G1, LN1res) -> Y1b bf16 (G4->LN2)
//  [16,22) WqkvT (prep->G1)  \
//  [22,24) WoT (prep->G2)    /-> X1b bf16 [16,24) (LN1->G3,LN2)
//  [24,40) QKb (G1->attn)        -> SA0b [24,32) + SA1b [32,40) (G2->LN1)
//                                -> Hb[lo] (G3->G4)
//  [40,48) Vt  (G1->attn)        -> Hb[mid]
//  [48,56) bqkv (prep->G1)       -> Cb (attn->G2)       -> Hb[hi]
//  [56,64) W2T (prep->G4)
// ---------------------------------------------------------------------------
extern "C" void kernel_launch(void* const* d_in, const int* in_sizes, int n_in,
                              void* d_out, int out_size, void* d_ws, size_t ws_size,
                              hipStream_t stream)
{
  (void)in_sizes; (void)n_in; (void)out_size; (void)ws_size;
  const float* x   = (const float*)d_in[0];
  const float* Wq  = (const float*)d_in[1];
  const float* bq  = (const float*)d_in[2];
  const float* Wk  = (const float*)d_in[3];
  const float* bk  = (const float*)d_in[4];
  const float* Wv  = (const float*)d_in[5];
  const float* bv  = (const float*)d_in[6];
  const float* Wo  = (const float*)d_in[7];
  const float* bo  = (const float*)d_in[8];
  const float* W1  = (const float*)d_in[9];
  const float* b1  = (const float*)d_in[10];
  const float* W2  = (const float*)d_in[11];
  const float* b2  = (const float*)d_in[12];
  const float* g1  = (const float*)d_in[13];
  const float* be1 = (const float*)d_in[14];
  const float* g2  = (const float*)d_in[15];
  const float* be2 = (const float*)d_in[16];

  char* ws = (char*)d_ws;
  const size_t MB = 1048576;
  u16*   W1T   = (u16*)(ws + 0 * MB);
  u16*   Y0b   = (u16*)(ws + 0 * MB);
  u16*   xb    = (u16*)(ws + 8 * MB);
  u16*   Y1b   = (u16*)(ws + 8 * MB);
  u16*   WqkvT = (u16*)(ws + 16 * MB);
  u16*   X1b   = (u16*)(ws + 16 * MB);
  u16*   WoT   = (u16*)(ws + 22 * MB);
  u16*   QKb   = (u16*)(ws + 24 * MB);
  u16*   SA0b  = (u16*)(ws + 24 * MB);
  u16*   SA1b  = (u16*)(ws + 32 * MB);
  u16*   Hb    = (u16*)(ws + 24 * MB);
  u16*   Vt    = (u16*)(ws + 40 * MB);
  float* bqkv  = (float*)(ws + 48 * MB);
  u16*   Cb    = (u16*)(ws + 48 * MB);
  u16*   W2T   = (u16*)(ws + 56 * MB);
  float* yout  = (float*)d_out;

  dim3 blk(256);
  // fused prep (one launch)
  prep_kernel<<<7180, blk, 0, stream>>>(Wq, Wk, Wv, Wo, W1, W2, x, bq, bk, bv,
                                        WqkvT, WoT, W1T, W2T, xb, bqkv);
  // G1: fused QKV projection (Q,K -> QKb; V -> Vt transposed, packed)
  gemm_kernel<0><<<dim3(24, 32, 1), blk, 0, stream>>>(xb, WqkvT, bqkv, QKb, Vt, 3072, 1024, 1024);
  // attention
  attn_kernel<<<dim3(32, 16, 2), blk, 0, stream>>>(QKb, Vt, Cb);
  // G2: sa = ctx @ Wo + bo, split-K=2 (bf16 partials)
  gemm_kernel<2><<<dim3(8, 32, 2), blk, 0, stream>>>(Cb, WoT, bo, SA0b, SA1b, 1024, 1024, 512);
  // LN1: x1 = LN(sa0 + sa1 + xb) -> bf16
  ln_kernel<0><<<4096, blk, 0, stream>>>(SA0b, SA1b, xb, g1, be1, X1b);
  // G3: h = gelu(x1 @ W1 + b1)
  gemm_kernel<1><<<dim3(32, 32, 1), blk, 0, stream>>>(X1b, W1T, b1, Hb, nullptr, 4096, 1024, 1024);
  // G4: y = h @ W2 + b2, split-K=2 (bf16 partials)
  gemm_kernel<2><<<dim3(8, 32, 2), blk, 0, stream>>>(Hb, W2T, b2, Y0b, Y1b, 1024, 4096, 2048);
  // LN2: out = LN(y0 + y1 + x1) -> fp32 d_out
  ln_kernel<1><<<4096, blk, 0, stream>>>(Y0b, Y1b, X1b, g2, be2, yout);
}

// Round 7
// 315.536 us; speedup vs baseline: 1.6914x; 1.6914x over previous
//
#include <hip/hip_runtime.h>
#include <cstdint>
#include <math.h>

typedef unsigned short u16;
typedef __attribute__((ext_vector_type(8))) short bf16x8;  // 8 bf16 (4 VGPRs)
typedef __attribute__((ext_vector_type(4))) float f32x4;   // MFMA acc

#define DEVI __device__ __forceinline__

DEVI u16 f2bf(float f) {
  union { float f; uint32_t u; } v; v.f = f;
  return (u16)((v.u + 0x7FFFu + ((v.u >> 16) & 1u)) >> 16);  // RNE
}
DEVI float bf2f(u16 h) {
  union { uint32_t u; float f; } v; v.u = ((uint32_t)h) << 16;
  return v.f;
}

// async global->LDS, 16B per lane. LDS dst = wave-uniform base + lane*16.
DEVI void gload16(const void* g, void* l) {
  __builtin_amdgcn_global_load_lds(
      (const __attribute__((address_space(1))) void*)g,
      (__attribute__((address_space(3))) void*)l, 16, 0, 0);
}

// tanh-form GELU: u*(1 - 1/(1+e^{2*0.79788456*(u+0.044715u^3)}))
DEVI float gelu_fast(float u) {
  float u2 = u * u;
  float t = __builtin_fmaf(0.044715f * u2, u, u);
  float e = __expf(1.5957691216057308f * t);
  float r = __builtin_amdgcn_rcpf(1.0f + e);
  return u - u * r;
}

// ---------------------------------------------------------------------------
// fp32 W[K][N] -> bf16 Wt[N][K] transpose-convert, one 64x64 tile via LDS
// ---------------------------------------------------------------------------
DEVI void tcvt_body(const float* __restrict__ W, u16* __restrict__ Wt,
                    int Kd, int N, int n0, int k0, float* t) {
  const int r = threadIdx.x >> 4, c4 = (threadIdx.x & 15) * 4;
#pragma unroll
  for (int p = 0; p < 4; ++p) {
    int row = p * 16 + r;
    float4 f = *(const float4*)(W + (size_t)(k0 + row) * N + n0 + c4);
    *(float4*)&t[row * 68 + c4] = f;
  }
  __syncthreads();
#pragma unroll
  for (int p = 0; p < 4; ++p) {
    int n = p * 16 + r;
    float v0 = t[(c4 + 0) * 68 + n];
    float v1 = t[(c4 + 1) * 68 + n];
    float v2 = t[(c4 + 2) * 68 + n];
    float v3 = t[(c4 + 3) * 68 + n];
    uint32_t lo = (uint32_t)f2bf(v0) | ((uint32_t)f2bf(v1) << 16);
    uint32_t hi = (uint32_t)f2bf(v2) | ((uint32_t)f2bf(v3) << 16);
    *(uint2*)(Wt + (size_t)(n0 + n) * Kd + k0 + c4) = make_uint2(lo, hi);
  }
}

// ---------------------------------------------------------------------------
// Fused prep: all weight transpose-converts + x convert + bias concat.
// grid.x = 7180: [0,1024) Wq/Wk/Wv/Wo; [1024,2048) W1; [2048,3072) W2;
// [3072,7168) x cvt; [7168,7180) bias concat.
// ---------------------------------------------------------------------------
__global__ __launch_bounds__(256)
void prep_kernel(const float* __restrict__ Wq, const float* __restrict__ Wk,
                 const float* __restrict__ Wv, const float* __restrict__ Wo,
                 const float* __restrict__ W1, const float* __restrict__ W2,
                 const float* __restrict__ x, const float* __restrict__ bq,
                 const float* __restrict__ bk, const float* __restrict__ bv,
                 u16* __restrict__ WqkvT, u16* __restrict__ WoT,
                 u16* __restrict__ W1T, u16* __restrict__ W2T,
                 u16* __restrict__ xb, float* __restrict__ bqkv)
{
  __shared__ float t[64 * 68];
  const int b = blockIdx.x;
  if (b < 1024) {
    int wsel = b >> 8, tt = b & 255;
    const float* W = (wsel == 0) ? Wq : (wsel == 1) ? Wk : (wsel == 2) ? Wv : Wo;
    u16* dst = (wsel == 3) ? WoT : WqkvT + (size_t)wsel * 1024 * 1024;
    tcvt_body(W, dst, 1024, 1024, (tt & 15) * 64, (tt >> 4) * 64, t);
  } else if (b < 2048) {
    int tt = b - 1024;
    tcvt_body(W1, W1T, 1024, 4096, (tt & 63) * 64, (tt >> 6) * 64, t);
  } else if (b < 3072) {
    int tt = b - 2048;
    tcvt_body(W2, W2T, 4096, 1024, (tt & 15) * 64, (tt >> 4) * 64, t);
  } else if (b < 7168) {
    int i = ((b - 3072) * 256 + threadIdx.x) * 4;
    float4 f = *(const float4*)(x + i);
    uint32_t lo = (uint32_t)f2bf(f.x) | ((uint32_t)f2bf(f.y) << 16);
    uint32_t hi = (uint32_t)f2bf(f.z) | ((uint32_t)f2bf(f.w) << 16);
    *(uint2*)(xb + i) = make_uint2(lo, hi);
  } else {
    int i = (b - 7168) * 256 + threadIdx.x;  // 0..3071
    const float* s = (i < 1024) ? bq : ((i < 2048) ? bk : bv);
    bqkv[i] = s[i & 1023];
  }
}

// ---------------------------------------------------------------------------
// GEMM: 128x128 tile, BK=64 (two stride-32 half-buffers), 256 thr (4 waves).
// SINGLE MFMA order everywhere (swapped): acc[i][j] = D[n][m] — lane holds 4
// consecutive n for fixed m. (R6 lesson: dual operand orders behind a runtime
// branch in the K-loop demote acc from AGPR to scratch -> 780 MB spill traffic.)
//   m_global = m0 + wm + i*16 + (lane&15);  n_global = n0 + wn + j*16 + rq + r
// MODE 0: fused QKV — n0<2048 -> QKb[m][n] bf16+bias (packed along n);
//         n0>=2048 -> Vt[n-2048][m] (scalar 2B stores, transposed).
// MODE 1: bf16 out + bias + fast GELU.
// MODE 2: split-K gridDim.z=2; z0 -> bf16+bias to C0; z1 -> bf16 raw to C1.
// L2 supertile swizzle: GROUP=8 m-tiles per band.
// ---------------------------------------------------------------------------
template<int MODE>
__global__ __launch_bounds__(256, 4)
void gemm_kernel(const u16* __restrict__ A, const u16* __restrict__ Bt,
                 const float* __restrict__ bias, void* __restrict__ C0,
                 void* __restrict__ C1, int N, int Kfull, int Kpart)
{
  __shared__ u16 As0[128 * 32], As1[128 * 32];
  __shared__ u16 Bs0[128 * 32], Bs1[128 * 32];
  const int tid = threadIdx.x;
  // supertile swizzle (8 m-tiles per band)
  const int nbx = gridDim.x, nby = gridDim.y;
  int lin = blockIdx.y * nbx + blockIdx.x;
  int band = lin / (8 * nbx);
  int rem = lin - band * (8 * nbx);
  int gsz = min(nby - band * 8, 8);
  const int m0 = (band * 8 + rem % gsz) * 128;
  const int n0 = (rem / gsz) * 128;
  const int kbase = (MODE == 2) ? (int)blockIdx.z * Kpart : 0;
  const int w = tid >> 6, lane = tid & 63;
  const int wm = (w >> 1) * 64, wn = (w & 1) * 64;
  const int mr = lane & 15, ko = (lane >> 4) * 8;
  const int rq = (lane >> 4) * 4;
  const int w32 = w * 32;

  f32x4 acc[4][4];
#pragma unroll
  for (int i = 0; i < 4; ++i)
#pragma unroll
    for (int j = 0; j < 4; ++j) {
      f32x4 z = {0.f, 0.f, 0.f, 0.f};
      acc[i][j] = z;
    }

  // staging: per gload16, 64 lanes cover 16 rows x 32 k (u16)
  const int lr = lane >> 2, lk = (lane & 3) * 8;
  const u16* aG = A  + (size_t)(m0 + w32 + lr) * Kfull + kbase + lk;
  const u16* bG = Bt + (size_t)(n0 + w32 + lr) * Kfull + kbase + lk;
  u16* aD00 = &As0[(w32 +  0) * 32];
  u16* aD01 = &As0[(w32 + 16) * 32];
  u16* aD10 = &As1[(w32 +  0) * 32];
  u16* aD11 = &As1[(w32 + 16) * 32];
  u16* bD00 = &Bs0[(w32 +  0) * 32];
  u16* bD01 = &Bs0[(w32 + 16) * 32];
  u16* bD10 = &Bs1[(w32 +  0) * 32];
  u16* bD11 = &Bs1[(w32 + 16) * 32];
  const size_t row16 = (size_t)16 * Kfull;

  for (int k0 = 0; k0 < Kpart; k0 += 64) {
    gload16(aG + k0,              aD00);
    gload16(aG + row16 + k0,      aD01);
    gload16(aG + k0 + 32,         aD10);
    gload16(aG + row16 + k0 + 32, aD11);
    gload16(bG + k0,              bD00);
    gload16(bG + row16 + k0,      bD01);
    gload16(bG + k0 + 32,         bD10);
    gload16(bG + row16 + k0 + 32, bD11);
    __syncthreads();
#pragma unroll
    for (int s = 0; s < 2; ++s) {
      const u16* Ap = s ? As1 : As0;
      const u16* Bp = s ? Bs1 : Bs0;
      bf16x8 af[4], bf[4];
#pragma unroll
      for (int i = 0; i < 4; ++i)
        af[i] = *(const bf16x8*)&Ap[(wm + i * 16 + mr) * 32 + ko];
#pragma unroll
      for (int j = 0; j < 4; ++j)
        bf[j] = *(const bf16x8*)&Bp[(wn + j * 16 + mr) * 32 + ko];
#pragma unroll
      for (int i = 0; i < 4; ++i)
#pragma unroll
        for (int j = 0; j < 4; ++j)
          acc[i][j] = __builtin_amdgcn_mfma_f32_16x16x32_bf16(bf[j], af[i], acc[i][j], 0, 0, 0);
    }
    __syncthreads();
  }

  if (MODE == 0) {
    if (n0 < 2048) {  // Q,K -> QKb [4096][2048], packed along n
#pragma unroll
      for (int i = 0; i < 4; ++i) {
        size_t mrow = (size_t)(m0 + wm + i * 16 + mr) * 2048;
#pragma unroll
        for (int j = 0; j < 4; ++j) {
          int nb = n0 + wn + j * 16 + rq;
          float4 b4 = *(const float4*)&bias[nb];
          uint32_t lo = (uint32_t)f2bf(acc[i][j][0] + b4.x) |
                        ((uint32_t)f2bf(acc[i][j][1] + b4.y) << 16);
          uint32_t hi = (uint32_t)f2bf(acc[i][j][2] + b4.z) |
                        ((uint32_t)f2bf(acc[i][j][3] + b4.w) << 16);
          *(uint2*)((u16*)C0 + mrow + nb) = make_uint2(lo, hi);
        }
      }
    } else {          // V -> Vt [1024][4096] transposed (scalar 2B stores)
#pragma unroll
      for (int i = 0; i < 4; ++i) {
        int mg = m0 + wm + i * 16 + mr;
#pragma unroll
        for (int j = 0; j < 4; ++j) {
          int nb = n0 + wn + j * 16 + rq;
          float4 b4 = *(const float4*)&bias[nb];
          int d = nb - 2048;
          ((u16*)C1)[(size_t)(d + 0) * 4096 + mg] = f2bf(acc[i][j][0] + b4.x);
          ((u16*)C1)[(size_t)(d + 1) * 4096 + mg] = f2bf(acc[i][j][1] + b4.y);
          ((u16*)C1)[(size_t)(d + 2) * 4096 + mg] = f2bf(acc[i][j][2] + b4.z);
          ((u16*)C1)[(size_t)(d + 3) * 4096 + mg] = f2bf(acc[i][j][3] + b4.w);
        }
      }
    }
  } else {
    const bool part1 = (MODE == 2) && (blockIdx.z == 1);
#pragma unroll
    for (int i = 0; i < 4; ++i) {
      size_t mrow = (size_t)(m0 + wm + i * 16 + mr) * N;
#pragma unroll
      for (int j = 0; j < 4; ++j) {
        int nb = n0 + wn + j * 16 + rq;
        float v0 = acc[i][j][0], v1 = acc[i][j][1];
        float v2 = acc[i][j][2], v3 = acc[i][j][3];
        if (!part1) {
          float4 b4 = *(const float4*)&bias[nb];
          v0 += b4.x; v1 += b4.y; v2 += b4.z; v3 += b4.w;
        }
        if (MODE == 1) {
          v0 = gelu_fast(v0); v1 = gelu_fast(v1);
          v2 = gelu_fast(v2); v3 = gelu_fast(v3);
        }
        uint32_t lo = (uint32_t)f2bf(v0) | ((uint32_t)f2bf(v1) << 16);
        uint32_t hi = (uint32_t)f2bf(v2) | ((uint32_t)f2bf(v3) << 16);
        u16* dst = part1 ? (u16*)C1 : (u16*)C0;
        *(uint2*)(dst + mrow + nb) = make_uint2(lo, hi);
      }
    }
  }
}

// ---------------------------------------------------------------------------
// Banded MFMA flash attention, simplified softmax. QK^T swapped -> S[t][q]:
// lane owns ONE q -> packed b64 P-writes, scalar l. PV swapped -> O[d][q].
// ---------------------------------------------------------------------------
__global__ __launch_bounds__(256)
void attn_kernel(const u16* __restrict__ QKb, const u16* __restrict__ Vt,
                 u16* __restrict__ ctx)
{
  const int KS = 2048, HD = 1024;
  __shared__ u16 Qs[64 * 80];
  __shared__ u16 Ks[64 * 80];
  __shared__ u16 Vts[64 * 72];   // [d][t]
  __shared__ u16 Ps[64 * 72];    // [q][t]

  const int qt = blockIdx.x, hh = blockIdx.y, bb = blockIdx.z;
  const int s0 = qt * 64;
  const int tid = threadIdx.x, w = tid >> 6, lane = tid & 63;
  const int mr = lane & 15, ko = (lane >> 4) * 8, rq = (lane >> 4) * 4;
  const int sr = tid >> 3, sc = (tid & 7) * 8;
  const int vrow = tid >> 2, vtc = (tid & 3) * 16;
  const float qsc = 0.022097086912079608f;  // 1/sqrt(2048)
  const int qg = s0 + w * 16 + mr;          // this lane's query row

#pragma unroll
  for (int p = 0; p < 2; ++p) {
    int row = p * 32 + sr;
    uint4 u = *(const uint4*)(QKb + (size_t)(bb * KS + s0 + row) * 2048 + hh * 64 + sc);
    *(uint4*)&Qs[row * 80 + sc] = u;
  }

  f32x4 accO[4];
#pragma unroll
  for (int j = 0; j < 4; ++j) { f32x4 z = {0.f,0.f,0.f,0.f}; accO[j] = z; }
  float lsum = 0.f;

  for (int c = 0; c < 9; ++c) {
    int tb = s0 - 256 + c * 64;
    if (tb < 0 || tb >= KS) continue;
    __syncthreads();
#pragma unroll
    for (int p = 0; p < 2; ++p) {
      int row = p * 32 + sr;
      uint4 uk = *(const uint4*)(QKb + (size_t)(bb * KS + tb + row) * 2048 + 1024 + hh * 64 + sc);
      *(uint4*)&Ks[row * 80 + sc] = uk;
    }
    {
      const u16* vsrc = Vt + (size_t)(hh * 64 + vrow) * 4096 + bb * KS + tb + vtc;
      *(uint4*)&Vts[vrow * 72 + vtc]     = *(const uint4*)vsrc;
      *(uint4*)&Vts[vrow * 72 + vtc + 8] = *(const uint4*)(vsrc + 8);
    }
    __syncthreads();

    // S = K Q^T (swapped): sacc[j] holds S[t= tb+j*16+rq+r][q= qg]
    f32x4 sacc[4];
#pragma unroll
    for (int j = 0; j < 4; ++j) { f32x4 z = {0.f,0.f,0.f,0.f}; sacc[j] = z; }
#pragma unroll
    for (int s = 0; s < 2; ++s) {
      bf16x8 aq = *(const bf16x8*)&Qs[(w * 16 + mr) * 80 + s * 32 + ko];
#pragma unroll
      for (int j = 0; j < 4; ++j) {
        bf16x8 bk = *(const bf16x8*)&Ks[(j * 16 + mr) * 80 + s * 32 + ko];
        sacc[j] = __builtin_amdgcn_mfma_f32_16x16x32_bf16(bk, aq, sacc[j], 0, 0, 0);
      }
    }

    // p = expf(s) (bounded scores); packed b64 P-writes; scalar l per lane
#pragma unroll
    for (int j = 0; j < 4; ++j) {
      int tgb = tb + j * 16 + rq;
      float p0, p1, p2, p3;
      {
        int d0 = qg - tgb;
        float s_ = sacc[j][0] * qsc;
        p0 = (d0 > 256 || d0 < -256) ? 0.f : __expf(s_);
        int d1 = d0 - 1; s_ = sacc[j][1] * qsc;
        p1 = (d1 > 256 || d1 < -256) ? 0.f : __expf(s_);
        int d2 = d0 - 2; s_ = sacc[j][2] * qsc;
        p2 = (d2 > 256 || d2 < -256) ? 0.f : __expf(s_);
        int d3 = d0 - 3; s_ = sacc[j][3] * qsc;
        p3 = (d3 > 256 || d3 < -256) ? 0.f : __expf(s_);
      }
      lsum += p0 + p1 + p2 + p3;
      uint32_t lo = (uint32_t)f2bf(p0) | ((uint32_t)f2bf(p1) << 16);
      uint32_t hi = (uint32_t)f2bf(p2) | ((uint32_t)f2bf(p3) << 16);
      *(uint2*)&Ps[(w * 16 + mr) * 72 + j * 16 + rq] = make_uint2(lo, hi);
    }
    // O += V^T P^T (swapped): accO[j] = O[d= j*16+rq+r][q= qg]
#pragma unroll
    for (int s = 0; s < 2; ++s) {
      bf16x8 ap = *(const bf16x8*)&Ps[(w * 16 + mr) * 72 + s * 32 + ko];
#pragma unroll
      for (int j = 0; j < 4; ++j) {
        bf16x8 bv = *(const bf16x8*)&Vts[(j * 16 + mr) * 72 + s * 32 + ko];
        accO[j] = __builtin_amdgcn_mfma_f32_16x16x32_bf16(bv, ap, accO[j], 0, 0, 0);
      }
    }
  }

  float l = lsum;
  l += __shfl_xor(l, 16, 64);
  l += __shfl_xor(l, 32, 64);
  float inv = 1.f / l;
  size_t base = (size_t)(bb * KS + qg) * HD + hh * 64;
#pragma unroll
  for (int j = 0; j < 4; ++j) {
    uint32_t lo = (uint32_t)f2bf(accO[j][0] * inv) | ((uint32_t)f2bf(accO[j][1] * inv) << 16);
    uint32_t hi = (uint32_t)f2bf(accO[j][2] * inv) | ((uint32_t)f2bf(accO[j][3] * inv) << 16);
    *(uint2*)(ctx + base + j * 16 + rq) = make_uint2(lo, hi);
  }
}

// ---------------------------------------------------------------------------
// LayerNorm(p0 + p1 + res) over D=1024; all inputs bf16.
// OUT32=0 -> bf16 out; OUT32=1 -> fp32 out.
// ---------------------------------------------------------------------------
DEVI void bfadd4(const u16* p, size_t base, float& v0, float& v1, float& v2, float& v3) {
  uint2 u = *(const uint2*)(p + base);
  v0 += bf2f((u16)(u.x & 0xFFFFu));
  v1 += bf2f((u16)(u.x >> 16));
  v2 += bf2f((u16)(u.y & 0xFFFFu));
  v3 += bf2f((u16)(u.y >> 16));
}

template<int OUT32>
__global__ __launch_bounds__(256)
void ln_kernel(const u16* __restrict__ p0, const u16* __restrict__ p1,
               const u16* __restrict__ res, const float* __restrict__ g,
               const float* __restrict__ be, void* __restrict__ out)
{
  __shared__ float red[8];
  const int row = blockIdx.x, tid = threadIdx.x;
  const int w = tid >> 6, lane = tid & 63;
  size_t base = (size_t)row * 1024 + tid * 4;
  float v0 = 0.f, v1 = 0.f, v2 = 0.f, v3 = 0.f;
  bfadd4(p0, base, v0, v1, v2, v3);
  bfadd4(p1, base, v0, v1, v2, v3);
  bfadd4(res, base, v0, v1, v2, v3);
  float s1 = v0 + v1 + v2 + v3;
  float s2 = v0 * v0 + v1 * v1 + v2 * v2 + v3 * v3;
#pragma unroll
  for (int o = 32; o > 0; o >>= 1) {
    s1 += __shfl_xor(s1, o, 64);
    s2 += __shfl_xor(s2, o, 64);
  }
  if (lane == 0) { red[w] = s1; red[4 + w] = s2; }
  __syncthreads();
  s1 = red[0] + red[1] + red[2] + red[3];
  s2 = red[4] + red[5] + red[6] + red[7];
  float mu = s1 * (1.f / 1024.f);
  float var = s2 * (1.f / 1024.f) - mu * mu;
  float rs = rsqrtf(var + 1e-5f);
  float4 gv = *(const float4*)(g + tid * 4);
  float4 bv = *(const float4*)(be + tid * 4);
  float o0 = (v0 - mu) * rs * gv.x + bv.x;
  float o1 = (v1 - mu) * rs * gv.y + bv.y;
  float o2 = (v2 - mu) * rs * gv.z + bv.z;
  float o3 = (v3 - mu) * rs * gv.w + bv.w;
  if (OUT32) {
    float4 ov; ov.x = o0; ov.y = o1; ov.z = o2; ov.w = o3;
    *(float4*)((float*)out + base) = ov;
  } else {
    uint32_t lo = (uint32_t)f2bf(o0) | ((uint32_t)f2bf(o1) << 16);
    uint32_t hi = (uint32_t)f2bf(o2) | ((uint32_t)f2bf(o3) << 16);
    *(uint2*)((u16*)out + base) = make_uint2(lo, hi);
  }
}

// ---------------------------------------------------------------------------
// ws layout (64 MiB), MiB offsets, lifetime-verified:
//  [0,8)   W1T (prep->G3)        -> Y0b bf16 (G4->LN2)
//  [8,16)  xb (prep->G1, LN1res) -> Y1b bf16 (G4->LN2)
//  [16,22) WqkvT (prep->G1)  \
//  [22,24) WoT (prep->G2)    /-> X1b bf16 [16,24) (LN1->G3,LN2)
//  [24,40) QKb (G1->attn)        -> SA0b [24,32) + SA1b [32,40) (G2->LN1)
//                                -> Hb[lo] (G3->G4)
//  [40,48) Vt  (G1->attn)        -> Hb[mid]
//  [48,56) bqkv (prep->G1)       -> Cb (attn->G2)       -> Hb[hi]
//  [56,64) W2T (prep->G4)
// ---------------------------------------------------------------------------
extern "C" void kernel_launch(void* const* d_in, const int* in_sizes, int n_in,
                              void* d_out, int out_size, void* d_ws, size_t ws_size,
                              hipStream_t stream)
{
  (void)in_sizes; (void)n_in; (void)out_size; (void)ws_size;
  const float* x   = (const float*)d_in[0];
  const float* Wq  = (const float*)d_in[1];
  const float* bq  = (const float*)d_in[2];
  const float* Wk  = (const float*)d_in[3];
  const float* bk  = (const float*)d_in[4];
  const float* Wv  = (const float*)d_in[5];
  const float* bv  = (const float*)d_in[6];
  const float* Wo  = (const float*)d_in[7];
  const float* bo  = (const float*)d_in[8];
  const float* W1  = (const float*)d_in[9];
  const float* b1  = (const float*)d_in[10];
  const float* W2  = (const float*)d_in[11];
  const float* b2  = (const float*)d_in[12];
  const float* g1  = (const float*)d_in[13];
  const float* be1 = (const float*)d_in[14];
  const float* g2  = (const float*)d_in[15];
  const float* be2 = (const float*)d_in[16];

  char* ws = (char*)d_ws;
  const size_t MB = 1048576;
  u16*   W1T   = (u16*)(ws + 0 * MB);
  u16*   Y0b   = (u16*)(ws + 0 * MB);
  u16*   xb    = (u16*)(ws + 8 * MB);
  u16*   Y1b   = (u16*)(ws + 8 * MB);
  u16*   WqkvT = (u16*)(ws + 16 * MB);
  u16*   X1b   = (u16*)(ws + 16 * MB);
  u16*   WoT   = (u16*)(ws + 22 * MB);
  u16*   QKb   = (u16*)(ws + 24 * MB);
  u16*   SA0b  = (u16*)(ws + 24 * MB);
  u16*   SA1b  = (u16*)(ws + 32 * MB);
  u16*   Hb    = (u16*)(ws + 24 * MB);
  u16*   Vt    = (u16*)(ws + 40 * MB);
  float* bqkv  = (float*)(ws + 48 * MB);
  u16*   Cb    = (u16*)(ws + 48 * MB);
  u16*   W2T   = (u16*)(ws + 56 * MB);
  float* yout  = (float*)d_out;

  dim3 blk(256);
  // fused prep (one launch)
  prep_kernel<<<7180, blk, 0, stream>>>(Wq, Wk, Wv, Wo, W1, W2, x, bq, bk, bv,
                                        WqkvT, WoT, W1T, W2T, xb, bqkv);
  // G1: fused QKV projection (Q,K -> QKb; V -> Vt transposed)
  gemm_kernel<0><<<dim3(24, 32, 1), blk, 0, stream>>>(xb, WqkvT, bqkv, QKb, Vt, 3072, 1024, 1024);
  // attention
  attn_kernel<<<dim3(32, 16, 2), blk, 0, stream>>>(QKb, Vt, Cb);
  // G2: sa = ctx @ Wo + bo, split-K=2 (bf16 partials)
  gemm_kernel<2><<<dim3(8, 32, 2), blk, 0, stream>>>(Cb, WoT, bo, SA0b, SA1b, 1024, 1024, 512);
  // LN1: x1 = LN(sa0 + sa1 + xb) -> bf16
  ln_kernel<0><<<4096, blk, 0, stream>>>(SA0b, SA1b, xb, g1, be1, X1b);
  // G3: h = gelu(x1 @ W1 + b1)
  gemm_kernel<1><<<dim3(32, 32, 1), blk, 0, stream>>>(X1b, W1T, b1, Hb, nullptr, 4096, 1024, 1024);
  // G4: y = h @ W2 + b2, split-K=2 (bf16 partials)
  gemm_kernel<2><<<dim3(8, 32, 2), blk, 0, stream>>>(Hb, W2T, b2, Y0b, Y1b, 1024, 4096, 2048);
  // LN2: out = LN(y0 + y1 + x1) -> fp32 d_out
  ln_kernel<1><<<4096, blk, 0, stream>>>(Y0b, Y1b, X1b, g2, be2, yout);
}